// Round 4
// baseline (80.970 us; speedup 1.0000x reference)
//
#include <hip/hip_runtime.h>
#include <math.h>

constexpr int B = 4, C = 64, H = 80, W = 80;
constexpr int HW = H * W;            // 6400
constexpr int NPIX = B * HW;         // 25600

typedef float f32x2 __attribute__((ext_vector_type(2)));
typedef unsigned u32;
typedef unsigned long long u64;

static __device__ __forceinline__ float silu(float v) {
    float e = __expf(-v);
    return v * __builtin_amdgcn_rcpf(1.0f + e);
}

// ---- packed u16 helpers (both GLCM channels in one instruction) -----------
static __device__ __forceinline__ u32 pks(u32 a, u32 b){u32 d; asm("v_pk_sub_u16 %0,%1,%2":"=v"(d):"v"(a),"v"(b)); return d;}
static __device__ __forceinline__ u32 pka(u32 a, u32 b){u32 d; asm("v_pk_add_u16 %0,%1,%2":"=v"(d):"v"(a),"v"(b)); return d;}
static __device__ __forceinline__ u32 pkm(u32 a, u32 b){u32 d; asm("v_pk_mul_lo_u16 %0,%1,%2":"=v"(d):"v"(a),"v"(b)); return d;}
static __device__ __forceinline__ u32 pkmin(u32 a, u32 b){u32 d; asm("v_pk_min_u16 %0,%1,%2":"=v"(d):"v"(a),"v"(b)); return d;}
static __device__ __forceinline__ u32 pkmaxi(u32 a, u32 b){u32 d; asm("v_pk_max_i16 %0,%1,%2":"=v"(d):"v"(a),"v"(b)); return d;}
static __device__ __forceinline__ float cb0(u32 a){float f; asm("v_cvt_f32_ubyte0 %0,%1":"=v"(f):"v"(a)); return f;}
static __device__ __forceinline__ float cb2(u32 a){float f; asm("v_cvt_f32_ubyte2 %0,%1":"=v"(f):"v"(a)); return f;}

// packed compare-exchange: both u16 halves sorted independently (2 channels)
static __device__ __forceinline__ void ce(u32 &x, u32 &y) {
    u32 mn, mx;
    asm("v_pk_min_u16 %0, %2, %3\n\t"
        "v_pk_max_u16 %1, %2, %3"
        : "=&v"(mn), "=v"(mx) : "v"(x), "v"(y));
    x = mn; y = mx;
}

// packed f32 FMA: acc.{lo,hi} += a.{lo,hi} * w.{lo,hi}; w = SGPR pair
// (weights for oc, oc+1 packed by pack_weights). 2 FLOP-pairs per instr.
static __device__ __forceinline__ void pkfma(f32x2 &acc, f32x2 a, u64 w){
    asm("v_pk_fma_f32 %0, %1, %2, %0" : "+v"(acc) : "v"(a), "s"(w));
}

// ---------------------------------------------------------------------------
// Kernel 0: reshape conv weights into oc-pair-packed u64 arrays.
//   out[p*L + j] = (w[(2p+1)*L+j] << 32) | w[2p*L+j]
// segments: cv1 16x68=1088, cv2 1088, m2 16x144=2304, cv3 32x64=2048 -> 6528
// ---------------------------------------------------------------------------
__global__ __launch_bounds__(256) void pack_weights(
    const float* __restrict__ w1, const float* __restrict__ w2,
    const float* __restrict__ wm2, const float* __restrict__ wc,
    u64* __restrict__ wp1, u64* __restrict__ wp2,
    u64* __restrict__ wpm2, u64* __restrict__ wpc) {
    const int i = blockIdx.x * 256 + threadIdx.x;
    auto pack2 = [](const float* w, int p, int L, int j) -> u64 {
        return ((u64)__float_as_uint(w[(2*p+1)*L + j]) << 32)
             | (u64)__float_as_uint(w[2*p*L + j]);
    };
    if (i < 1088)      wp1[i] = pack2(w1, i / 68, 68, i % 68);
    else if (i < 2176) { int k = i - 1088; wp2[k]  = pack2(w2,  k / 68,  68,  k % 68); }
    else if (i < 4480) { int k = i - 2176; wpm2[k] = pack2(wm2, k / 144, 144, k % 144); }
    else if (i < 6528) { int k = i - 4480; wpc[k]  = pack2(wc,  k / 64,  64,  k % 64); }
}

// ---------------------------------------------------------------------------
// Kernel 1: GLCM features. thread = (pixel, 2 channels), both channels packed
// into u16 halves of every int op. block 256 = 8 px x 32 ch-pairs.
// sort (packed Batcher) -> packed run-length scans give multiplicity m_a:
//   contrast = sum d^2/20   homog = sum 1/(1+|d|)/20
//   energy = (20 + 2*sum p_fwd)/400   entropy = -(20 log .05 + log prod m)/20
// ---------------------------------------------------------------------------
__global__ __launch_bounds__(256) void glcm_kernel(const float* __restrict__ x,
                                                   float* __restrict__ g) {
    const int t = threadIdx.x;
    const int pxl = t & 7;               // 0..7
    const int grp = t >> 3;              // 0..31 (channel pair)
    const int pix = blockIdx.x * 8 + pxl;
    const int b = pix / HW;
    const int hw = pix - b * HW;
    const int h = hw / W;
    const int w = hw - h * W;
    const int hm = h > 0 ? h - 1 : 0;
    const int hp = h < H - 1 ? h + 1 : H - 1;
    const int wm = w > 0 ? w - 1 : 0;
    const int wp = w < W - 1 ? w + 1 : W - 1;
    const int o[9] = {hm * W + wm, hm * W + w, hm * W + wp,
                      h  * W + wm, h  * W + w, h  * W + wp,
                      hp * W + wm, hp * W + w, hp * W + wp};
    const float* c0 = x + (size_t)(b * C + grp * 2) * HW;
    const float* c1 = c0 + HW;

    u32 qpk[9];
    #pragma unroll
    for (int k = 0; k < 9; ++k) {
        int a0 = (int)(c0[o[k]] * 7.0f);
        int a1 = (int)(c1[o[k]] * 7.0f);
        a0 = a0 < 0 ? 0 : (a0 > 7 ? 7 : a0);
        a1 = a1 < 0 ? 0 : (a1 > 7 ? 7 : a1);
        qpk[k] = (u32)a0 | ((u32)a1 << 16);
    }

    static constexpr int PA[20] = {0,1,3,4,6,7, 0,1,2,3,4,5, 0,1,3,4, 1,2,4,5};
    static constexpr int PB[20] = {1,2,4,5,7,8, 3,4,5,6,7,8, 4,5,7,8, 3,4,6,7};

    const u32 ONEpk = 0x00010001u, EIGHTpk = 0x00080008u;
    u32 cs = 0;                 // packed sum of d^2 per half (<=980)
    float hsum = 0.f;
    u32 key[20];
    #pragma unroll
    for (int a = 0; a < 20; ++a) {
        const u32 qa = qpk[PA[a]], qb = qpk[PB[a]];
        const u32 d = pks(qa, qb);                 // i16 wrap-safe
        cs = pka(cs, pkm(d, d));
        const u32 ad = pkmaxi(d, pks(0u, d));      // |d| per half 0..7
        const u32 h1 = pka(ad, ONEpk);             // 1..8, bytes 0 and 2
        hsum += __builtin_amdgcn_rcpf(cb0(h1)) + __builtin_amdgcn_rcpf(cb2(h1));
        key[a] = pka(pkm(qa, EIGHTpk), qb);        // qa*8+qb per half, <=63
    }

    // Batcher odd-even mergesort for n=32, pruned to the low 20 slots
    #pragma unroll
    for (int p = 1; p < 32; p <<= 1) {
        #pragma unroll
        for (int k = p; k >= 1; k >>= 1) {
            const int jm = k % p;
            #pragma unroll
            for (int lo = 0; lo < 20; ++lo) {
                const int hi = lo + k;
                if (hi < 20 && lo >= jm && ((lo - jm) % (2 * k)) < k &&
                    (lo / (2 * p)) == (hi / (2 * p))) {
                    ce(key[lo], key[hi]);
                }
            }
        }
    }

    // boundary flags: eq[a] = (key[a]==key[a-1]) per half as 0/1 (packed)
    u32 eq[20];
    #pragma unroll
    for (int a = 1; a < 20; ++a)
        eq[a] = pks(ONEpk, pkmin(pks(key[a], key[a - 1]), ONEpk));

    // forward run scan: pc = (pc+1)*eq  (packed), psum += pc
    u32 pc = 0, ps = 0, pv[20];
    pv[0] = 0;
    #pragma unroll
    for (int a = 1; a < 20; ++a) {
        pc = pkm(pka(pc, ONEpk), eq[a]);
        pv[a] = pc;
        ps = pka(ps, pc);
    }
    // backward run scan + multiplicity product: m = p + r + 1 (<=20, byte)
    float pr0, pr1;
    {
        const u32 m = pka(pv[19], ONEpk);
        pr0 = cb0(m); pr1 = cb2(m);
    }
    u32 rc = 0;
    #pragma unroll
    for (int a = 18; a >= 0; --a) {
        rc = pkm(pka(rc, ONEpk), eq[a + 1]);
        const u32 m = pka(pka(pv[a], rc), ONEpk);
        pr0 *= cb0(m); pr1 *= cb2(m);
    }

    const int csum = (int)(cs & 0xFFFFu) + (int)(cs >> 16);
    const int psum = (int)(ps & 0xFFFFu) + (int)(ps >> 16);
    const float lsum = __logf(pr0) + __logf(pr1);

    float fc = (float)csum * (1.f / 20.f);
    float fe = ((float)psum * 2.f + 40.f) * (1.f / 400.f);
    float fn = -(lsum + 40.f * -2.9957322736f /*log(0.05)*/) * (1.f / 20.f);
    float fh = hsum * (1.f / 20.f);

    // reduce over 8 channel-pairs within the wave (lane bits 3..5)
    #pragma unroll
    for (int m = 8; m < 64; m <<= 1) {
        fc += __shfl_xor(fc, m);
        fe += __shfl_xor(fe, m);
        fn += __shfl_xor(fn, m);
        fh += __shfl_xor(fh, m);
    }
    __shared__ float red[4][8][4];
    const int wv = t >> 6;
    if ((t & 63) < 8) {
        red[wv][pxl][0] = fc; red[wv][pxl][1] = fe;
        red[wv][pxl][2] = fn; red[wv][pxl][3] = fh;
    }
    __syncthreads();
    if (t < 32) {
        const int p2 = t >> 2, f = t & 3;
        float s = red[0][p2][f] + red[1][p2][f] + red[2][p2][f] + red[3][p2][f];
        s *= (1.f / 64.f);
        const int pix2 = blockIdx.x * 8 + p2;
        const int b2 = pix2 / HW;
        const int hw2 = pix2 - b2 * HW;
        g[((size_t)(b2 * 4 + f)) * HW + hw2] = s;
    }
}

// ---------------------------------------------------------------------------
// Kernel 2: cv1 + cv2 (1x1, 68->32 each) + BN + SiLU, then m1 (1x1, 32->16)
// fused via LDS tile. block 512 = 8 waves x 64 px. Wave w: oc [4w,4w+4) of
// cv1 AND cv2 as 2 oc-pairs each (v_pk_fma_f32); then 2 oc of m1 (scalar).
// ---------------------------------------------------------------------------
__global__ __launch_bounds__(512) void stage1_kernel(
    const float* __restrict__ x, const float* __restrict__ g,
    const u64* __restrict__ wp1, const float* __restrict__ s1, const float* __restrict__ b1,
    const u64* __restrict__ wp2, const float* __restrict__ s2, const float* __restrict__ b2,
    const float* __restrict__ wm1, const float* __restrict__ sm1, const float* __restrict__ bm1,
    float* __restrict__ a, float* __restrict__ bbuf, float* __restrict__ y16) {
    __shared__ float aT[32][64];
    const int t = threadIdx.x;
    const int lane = t & 63;
    const int wv = __builtin_amdgcn_readfirstlane(t >> 6);   // 0..7
    const int oc0 = wv * 4;
    const int p0 = wv * 2;                                   // oc-pair index
    const int pix = blockIdx.x * 64 + lane;
    const int bi = pix / HW;
    const int hw = pix - bi * HW;
    const float* xp = x + (size_t)(bi * C) * HW + hw;
    const float* gp = g + (size_t)(bi * 4) * HW + hw;

    f32x2 acc1[2] = {{0.f, 0.f}, {0.f, 0.f}};
    f32x2 acc2[2] = {{0.f, 0.f}, {0.f, 0.f}};
    #pragma unroll 8
    for (int ic = 0; ic < C; ++ic) {
        const float xv = xp[(size_t)ic * HW];
        const f32x2 av = {xv, xv};
        pkfma(acc1[0], av, wp1[(p0    ) * 68 + ic]);
        pkfma(acc1[1], av, wp1[(p0 + 1) * 68 + ic]);
        pkfma(acc2[0], av, wp2[(p0    ) * 68 + ic]);
        pkfma(acc2[1], av, wp2[(p0 + 1) * 68 + ic]);
    }
    #pragma unroll
    for (int ic = 0; ic < 4; ++ic) {
        const float gv = gp[(size_t)ic * HW];
        const f32x2 av = {gv, gv};
        pkfma(acc1[0], av, wp1[(p0    ) * 68 + 64 + ic]);
        pkfma(acc1[1], av, wp1[(p0 + 1) * 68 + 64 + ic]);
        pkfma(acc2[0], av, wp2[(p0    ) * 68 + 64 + ic]);
        pkfma(acc2[1], av, wp2[(p0 + 1) * 68 + 64 + ic]);
    }
    #pragma unroll
    for (int j = 0; j < 2; ++j) {
        #pragma unroll
        for (int hf = 0; hf < 2; ++hf) {
            const int oc = oc0 + j * 2 + hf;
            const float v1 = silu(acc1[j][hf] * s1[oc] + b1[oc]);
            a[((size_t)(bi * 32 + oc)) * HW + hw] = v1;
            aT[oc][lane] = v1;
            bbuf[((size_t)(bi * 32 + oc)) * HW + hw] = silu(acc2[j][hf] * s2[oc] + b2[oc]);
        }
    }
    __syncthreads();
    // m1: wave w computes oc [2w, 2w+2) (scalar fmac; pk gains nothing at 2 oc)
    const int om0 = wv * 2;
    float accm[2] = {0.f, 0.f};
    #pragma unroll 8
    for (int ic = 0; ic < 32; ++ic) {
        const float av = aT[ic][lane];
        #pragma unroll
        for (int j = 0; j < 2; ++j) accm[j] += av * wm1[(om0 + j) * 32 + ic];
    }
    #pragma unroll
    for (int j = 0; j < 2; ++j) {
        const int oc = om0 + j;
        y16[((size_t)(bi * 16 + oc)) * HW + hw] = silu(accm[j] * sm1[oc] + bm1[oc]);
    }
}

// ---------------------------------------------------------------------------
// Kernel 3: m2 (3x3, 16->32, pad 1) + BN + SiLU + residual (a), then cv3
// (1x1 over concat(a', b), 64->64) via LDS tile. block 512 = 8 waves x 64 px.
// Wave w: 2 oc-pairs of m2, then 4 oc-pairs of cv3 (v_pk_fma_f32).
// ---------------------------------------------------------------------------
__global__ __launch_bounds__(512) void m2cv3_kernel(
    const float* __restrict__ y16, const float* __restrict__ a,
    const float* __restrict__ bbuf,
    const u64* __restrict__ wpm2, const float* __restrict__ sm2, const float* __restrict__ bm2,
    const u64* __restrict__ wpc, const float* __restrict__ sc, const float* __restrict__ bc,
    float* __restrict__ out) {
    __shared__ float a2[32][64];
    const int t = threadIdx.x;
    const int lane = t & 63;
    const int wv = __builtin_amdgcn_readfirstlane(t >> 6);   // 0..7
    const int oc0 = wv * 4;
    const int pm0 = wv * 2;
    const int pix = blockIdx.x * 64 + lane;
    const int bi = pix / HW;
    const int hw = pix - bi * HW;
    const int h = hw / W;
    const int w = hw - h * W;
    const float* yp = y16 + (size_t)(bi * 16) * HW;

    f32x2 accm[2] = {{0.f, 0.f}, {0.f, 0.f}};
    for (int ic = 0; ic < 16; ++ic) {
        #pragma unroll
        for (int kh = 0; kh < 3; ++kh) {
            const int rr = h + kh - 1;
            const bool rin = (rr >= 0) && (rr < H);
            #pragma unroll
            for (int kw = 0; kw < 3; ++kw) {
                const int cc = w + kw - 1;
                const bool in = rin && (cc >= 0) && (cc < W);
                const float yv = in ? yp[(size_t)ic * HW + rr * W + cc] : 0.0f;
                const f32x2 yv2 = {yv, yv};
                const int j9 = ic * 9 + kh * 3 + kw;
                pkfma(accm[0], yv2, wpm2[(pm0    ) * 144 + j9]);
                pkfma(accm[1], yv2, wpm2[(pm0 + 1) * 144 + j9]);
            }
        }
    }
    #pragma unroll
    for (int j = 0; j < 2; ++j) {
        #pragma unroll
        for (int hf = 0; hf < 2; ++hf) {
            const int oc = oc0 + j * 2 + hf;
            const float v = a[((size_t)(bi * 32 + oc)) * HW + hw]
                          + silu(accm[j][hf] * sm2[oc] + bm2[oc]);
            a2[oc][lane] = v;
        }
    }
    __syncthreads();
    // cv3: wave w computes oc [8w, 8w+8) as 4 oc-pairs
    const int oc3 = wv * 8;
    const int pc0 = wv * 4;
    const float* bp = bbuf + (size_t)(bi * 32) * HW + hw;
    f32x2 acc3[4] = {{0.f, 0.f}, {0.f, 0.f}, {0.f, 0.f}, {0.f, 0.f}};
    #pragma unroll 8
    for (int ic = 0; ic < 32; ++ic) {
        const float av = a2[ic][lane];
        const f32x2 av2 = {av, av};
        #pragma unroll
        for (int j = 0; j < 4; ++j)
            pkfma(acc3[j], av2, wpc[(pc0 + j) * 64 + ic]);
    }
    #pragma unroll 8
    for (int ic = 0; ic < 32; ++ic) {
        const float bv = bp[(size_t)ic * HW];
        const f32x2 bv2 = {bv, bv};
        #pragma unroll
        for (int j = 0; j < 4; ++j)
            pkfma(acc3[j], bv2, wpc[(pc0 + j) * 64 + 32 + ic]);
    }
    #pragma unroll
    for (int j = 0; j < 4; ++j) {
        #pragma unroll
        for (int hf = 0; hf < 2; ++hf) {
            const int oc = oc3 + j * 2 + hf;
            out[((size_t)(bi * 64 + oc)) * HW + hw] = silu(acc3[j][hf] * sc[oc] + bc[oc]);
        }
    }
}

// ---------------------------------------------------------------------------
extern "C" void kernel_launch(void* const* d_in, const int* in_sizes, int n_in,
                              void* d_out, int out_size, void* d_ws, size_t ws_size,
                              hipStream_t stream) {
    const float* x    = (const float*)d_in[0];
    const float* cv1w = (const float*)d_in[1];
    const float* cv1s = (const float*)d_in[2];
    const float* cv1b = (const float*)d_in[3];
    const float* cv2w = (const float*)d_in[4];
    const float* cv2s = (const float*)d_in[5];
    const float* cv2b = (const float*)d_in[6];
    const float* m1w  = (const float*)d_in[7];
    const float* m1s  = (const float*)d_in[8];
    const float* m1b  = (const float*)d_in[9];
    const float* m2w  = (const float*)d_in[10];
    const float* m2s  = (const float*)d_in[11];
    const float* m2b  = (const float*)d_in[12];
    const float* cv3w = (const float*)d_in[13];
    const float* cv3s = (const float*)d_in[14];
    const float* cv3b = (const float*)d_in[15];

    float* ws   = (float*)d_ws;
    float* g    = ws;                 // 4*4*6400   = 102400 floats
    float* a    = ws + 102400;        // 4*32*6400  = 819200
    float* bbuf = ws + 921600;        // 4*32*6400  = 819200
    float* y16  = ws + 1740800;       // 4*16*6400  = 409600 (end 2150400)
    u64* wpbase = (u64*)(ws + 2150400);  // 8B-aligned (offset even)
    u64* wp1  = wpbase;               // 1088
    u64* wp2  = wpbase + 1088;        // 1088
    u64* wpm2 = wpbase + 2176;        // 2304
    u64* wpc  = wpbase + 4480;        // 2048 (end 6528 u64 = 13056 floats)

    pack_weights<<<26, 256, 0, stream>>>(cv1w, cv2w, m2w, cv3w,
                                         wp1, wp2, wpm2, wpc);
    glcm_kernel<<<NPIX / 8, 256, 0, stream>>>(x, g);
    stage1_kernel<<<NPIX / 64, 512, 0, stream>>>(x, g, wp1, cv1s, cv1b,
                                                 wp2, cv2s, cv2b,
                                                 m1w, m1s, m1b, a, bbuf, y16);
    m2cv3_kernel<<<NPIX / 64, 512, 0, stream>>>(y16, a, bbuf, wpm2, m2s, m2b,
                                                wpc, cv3s, cv3b, (float*)d_out);
}

// Round 5
// 71.860 us; speedup vs baseline: 1.1268x; 1.1268x over previous
//
#include <hip/hip_runtime.h>
#include <math.h>

constexpr int B = 4, C = 64, H = 80, W = 80;
constexpr int HW = H * W;            // 6400
constexpr int NPIX = B * HW;         // 25600
constexpr int GLCM_BLOCKS = NPIX / 8;  // 3200
constexpr int PACK_ELEMS = 2176 + 2176 + 512 + 4608 + 4096;  // 13568
constexpr int PACK_BLOCKS = PACK_ELEMS / 256;                // 53

typedef unsigned u32;

static __device__ __forceinline__ float silu(float v) {
    float e = __expf(-v);
    return v * __builtin_amdgcn_rcpf(1.0f + e);
}

// ---- packed u16 helpers (both GLCM channels in one instruction) -----------
static __device__ __forceinline__ u32 pks(u32 a, u32 b){u32 d; asm("v_pk_sub_u16 %0,%1,%2":"=v"(d):"v"(a),"v"(b)); return d;}
static __device__ __forceinline__ u32 pka(u32 a, u32 b){u32 d; asm("v_pk_add_u16 %0,%1,%2":"=v"(d):"v"(a),"v"(b)); return d;}
static __device__ __forceinline__ u32 pkm(u32 a, u32 b){u32 d; asm("v_pk_mul_lo_u16 %0,%1,%2":"=v"(d):"v"(a),"v"(b)); return d;}
static __device__ __forceinline__ u32 pkmin(u32 a, u32 b){u32 d; asm("v_pk_min_u16 %0,%1,%2":"=v"(d):"v"(a),"v"(b)); return d;}
static __device__ __forceinline__ u32 pkmaxi(u32 a, u32 b){u32 d; asm("v_pk_max_i16 %0,%1,%2":"=v"(d):"v"(a),"v"(b)); return d;}
static __device__ __forceinline__ float cb0(u32 a){float f; asm("v_cvt_f32_ubyte0 %0,%1":"=v"(f):"v"(a)); return f;}
static __device__ __forceinline__ float cb2(u32 a){float f; asm("v_cvt_f32_ubyte2 %0,%1":"=v"(f):"v"(a)); return f;}

// packed compare-exchange: both u16 halves sorted independently (2 channels)
static __device__ __forceinline__ void ce(u32 &x, u32 &y) {
    u32 mn, mx;
    asm("v_pk_min_u16 %0, %2, %3\n\t"
        "v_pk_max_u16 %1, %2, %3"
        : "=&v"(mn), "=v"(mx) : "v"(x), "v"(y));
    x = mn; y = mx;
}

// ---------------------------------------------------------------------------
// Kernel 1: GLCM features (blocks 0..3199), thread = (pixel, 2 channels),
// both channels packed into u16 halves. block 256 = 8 px x 32 ch-pairs.
// Blocks 3200.. also transpose conv weights to oc-contiguous layout
// (wt[ic][oc]) so conv kernels get merged wave-uniform s_load_dwordx2/x4.
// ---------------------------------------------------------------------------
__global__ __launch_bounds__(256) void glcm_kernel(
    const float* __restrict__ x, float* __restrict__ g,
    const float* __restrict__ w1, const float* __restrict__ w2,
    const float* __restrict__ wm1, const float* __restrict__ wm2,
    const float* __restrict__ wc,
    float* __restrict__ wt1, float* __restrict__ wt2,
    float* __restrict__ wtm1, float* __restrict__ wtm2,
    float* __restrict__ wtc) {
    if (blockIdx.x >= GLCM_BLOCKS) {
        // weight transpose: wt[ic*OC + oc] = w[oc*IC + ic]
        const int i = (blockIdx.x - GLCM_BLOCKS) * 256 + threadIdx.x;
        if (i < 2176)       wt1[i]  = w1[(i & 31) * 68 + (i >> 5)];
        else if (i < 4352)  { int k = i - 2176; wt2[k]  = w2[(k & 31) * 68 + (k >> 5)]; }
        else if (i < 4864)  { int k = i - 4352; wtm1[k] = wm1[(k & 15) * 32 + (k >> 4)]; }
        else if (i < 9472)  { int k = i - 4864; wtm2[k] = wm2[(k & 31) * 144 + (k >> 5)]; }
        else if (i < 13568) { int k = i - 9472; wtc[k]  = wc[(k & 63) * 64 + (k >> 6)]; }
        return;
    }
    const int t = threadIdx.x;
    const int pxl = t & 7;               // 0..7
    const int grp = t >> 3;              // 0..31 (channel pair)
    const int pix = blockIdx.x * 8 + pxl;
    const int b = pix / HW;
    const int hw = pix - b * HW;
    const int h = hw / W;
    const int w = hw - h * W;
    const int hm = h > 0 ? h - 1 : 0;
    const int hp = h < H - 1 ? h + 1 : H - 1;
    const int wm = w > 0 ? w - 1 : 0;
    const int wp = w < W - 1 ? w + 1 : W - 1;
    const int o[9] = {hm * W + wm, hm * W + w, hm * W + wp,
                      h  * W + wm, h  * W + w, h  * W + wp,
                      hp * W + wm, hp * W + w, hp * W + wp};
    const float* c0 = x + (size_t)(b * C + grp * 2) * HW;
    const float* c1 = c0 + HW;

    u32 qpk[9];
    #pragma unroll
    for (int k = 0; k < 9; ++k) {
        int a0 = (int)(c0[o[k]] * 7.0f);
        int a1 = (int)(c1[o[k]] * 7.0f);
        a0 = a0 < 0 ? 0 : (a0 > 7 ? 7 : a0);
        a1 = a1 < 0 ? 0 : (a1 > 7 ? 7 : a1);
        qpk[k] = (u32)a0 | ((u32)a1 << 16);
    }

    static constexpr int PA[20] = {0,1,3,4,6,7, 0,1,2,3,4,5, 0,1,3,4, 1,2,4,5};
    static constexpr int PB[20] = {1,2,4,5,7,8, 3,4,5,6,7,8, 4,5,7,8, 3,4,6,7};

    const u32 ONEpk = 0x00010001u, EIGHTpk = 0x00080008u;
    u32 cs = 0;                 // packed sum of d^2 per half (<=980)
    float hsum = 0.f;
    u32 key[20];
    #pragma unroll
    for (int a = 0; a < 20; ++a) {
        const u32 qa = qpk[PA[a]], qb = qpk[PB[a]];
        const u32 d = pks(qa, qb);                 // i16 wrap-safe
        cs = pka(cs, pkm(d, d));
        const u32 ad = pkmaxi(d, pks(0u, d));      // |d| per half 0..7
        const u32 h1 = pka(ad, ONEpk);             // 1..8, bytes 0 and 2
        hsum += __builtin_amdgcn_rcpf(cb0(h1)) + __builtin_amdgcn_rcpf(cb2(h1));
        key[a] = pka(pkm(qa, EIGHTpk), qb);        // qa*8+qb per half, <=63
    }

    // Batcher odd-even mergesort for n=32, pruned to the low 20 slots
    #pragma unroll
    for (int p = 1; p < 32; p <<= 1) {
        #pragma unroll
        for (int k = p; k >= 1; k >>= 1) {
            const int jm = k % p;
            #pragma unroll
            for (int lo = 0; lo < 20; ++lo) {
                const int hi = lo + k;
                if (hi < 20 && lo >= jm && ((lo - jm) % (2 * k)) < k &&
                    (lo / (2 * p)) == (hi / (2 * p))) {
                    ce(key[lo], key[hi]);
                }
            }
        }
    }

    // boundary flags: eq[a] = (key[a]==key[a-1]) per half as 0/1 (packed)
    u32 eq[20];
    #pragma unroll
    for (int a = 1; a < 20; ++a)
        eq[a] = pks(ONEpk, pkmin(pks(key[a], key[a - 1]), ONEpk));

    // forward run scan: pc = (pc+1)*eq  (packed), psum += pc
    u32 pc = 0, ps = 0, pv[20];
    pv[0] = 0;
    #pragma unroll
    for (int a = 1; a < 20; ++a) {
        pc = pkm(pka(pc, ONEpk), eq[a]);
        pv[a] = pc;
        ps = pka(ps, pc);
    }
    // backward run scan + multiplicity product: m = p + r + 1 (<=20, byte)
    float pr0, pr1;
    {
        const u32 m = pka(pv[19], ONEpk);
        pr0 = cb0(m); pr1 = cb2(m);
    }
    u32 rc = 0;
    #pragma unroll
    for (int a = 18; a >= 0; --a) {
        rc = pkm(pka(rc, ONEpk), eq[a + 1]);
        const u32 m = pka(pka(pv[a], rc), ONEpk);
        pr0 *= cb0(m); pr1 *= cb2(m);
    }

    const int csum = (int)(cs & 0xFFFFu) + (int)(cs >> 16);
    const int psum = (int)(ps & 0xFFFFu) + (int)(ps >> 16);
    const float lsum = __logf(pr0) + __logf(pr1);

    float fc = (float)csum * (1.f / 20.f);
    float fe = ((float)psum * 2.f + 40.f) * (1.f / 400.f);
    float fn = -(lsum + 40.f * -2.9957322736f /*log(0.05)*/) * (1.f / 20.f);
    float fh = hsum * (1.f / 20.f);

    // reduce over 8 channel-pairs within the wave (lane bits 3..5)
    #pragma unroll
    for (int m = 8; m < 64; m <<= 1) {
        fc += __shfl_xor(fc, m);
        fe += __shfl_xor(fe, m);
        fn += __shfl_xor(fn, m);
        fh += __shfl_xor(fh, m);
    }
    __shared__ float red[4][8][4];
    const int wv = t >> 6;
    if ((t & 63) < 8) {
        red[wv][pxl][0] = fc; red[wv][pxl][1] = fe;
        red[wv][pxl][2] = fn; red[wv][pxl][3] = fh;
    }
    __syncthreads();
    if (t < 32) {
        const int p2 = t >> 2, f = t & 3;
        float s = red[0][p2][f] + red[1][p2][f] + red[2][p2][f] + red[3][p2][f];
        s *= (1.f / 64.f);
        const int pix2 = blockIdx.x * 8 + p2;
        const int b2 = pix2 / HW;
        const int hw2 = pix2 - b2 * HW;
        g[((size_t)(b2 * 4 + f)) * HW + hw2] = s;
    }
}

// ---------------------------------------------------------------------------
// Kernel 2: cv1 + cv2 (1x1, 68->32 each) + BN + SiLU, then m1 (1x1, 32->16)
// fused via LDS tile. block 1024 = 16 waves x 64 px (16 waves/block for TLP;
// round-4 lesson: occupancy was grid-limited at 25%).
// Wave w: oc {2w, 2w+1} of cv1 AND cv2 — weights via oc-contiguous wt arrays
// so the compiler emits merged wave-uniform s_load_dwordx2 (scalar pipe) and
// v_fmac_f32 v,s,v. Then 1 oc of m1.
// ---------------------------------------------------------------------------
__global__ __launch_bounds__(1024) void stage1_kernel(
    const float* __restrict__ x, const float* __restrict__ g,
    const float* __restrict__ wt1, const float* __restrict__ s1, const float* __restrict__ b1,
    const float* __restrict__ wt2, const float* __restrict__ s2, const float* __restrict__ b2,
    const float* __restrict__ wtm1, const float* __restrict__ sm1, const float* __restrict__ bm1,
    float* __restrict__ a, float* __restrict__ bbuf, float* __restrict__ y16) {
    __shared__ float aT[32][64];
    const int t = threadIdx.x;
    const int lane = t & 63;
    const int wv = __builtin_amdgcn_readfirstlane(t >> 6);   // 0..15
    const int oc0 = wv * 2;
    const int pix = blockIdx.x * 64 + lane;
    const int bi = pix / HW;
    const int hw = pix - bi * HW;
    const float* xp = x + (size_t)(bi * C) * HW + hw;
    const float* gp = g + (size_t)(bi * 4) * HW + hw;

    float a10 = 0.f, a11 = 0.f, a20 = 0.f, a21 = 0.f;
    #pragma unroll 8
    for (int ic = 0; ic < C; ++ic) {
        const float xv = xp[(size_t)ic * HW];
        a10 += xv * wt1[ic * 32 + oc0];
        a11 += xv * wt1[ic * 32 + oc0 + 1];
        a20 += xv * wt2[ic * 32 + oc0];
        a21 += xv * wt2[ic * 32 + oc0 + 1];
    }
    #pragma unroll
    for (int ic = 0; ic < 4; ++ic) {
        const float gv = gp[(size_t)ic * HW];
        a10 += gv * wt1[(64 + ic) * 32 + oc0];
        a11 += gv * wt1[(64 + ic) * 32 + oc0 + 1];
        a20 += gv * wt2[(64 + ic) * 32 + oc0];
        a21 += gv * wt2[(64 + ic) * 32 + oc0 + 1];
    }
    {
        const float v0 = silu(a10 * s1[oc0] + b1[oc0]);
        const float v1 = silu(a11 * s1[oc0 + 1] + b1[oc0 + 1]);
        a[((size_t)(bi * 32 + oc0)) * HW + hw] = v0;
        a[((size_t)(bi * 32 + oc0 + 1)) * HW + hw] = v1;
        aT[oc0][lane] = v0;
        aT[oc0 + 1][lane] = v1;
        bbuf[((size_t)(bi * 32 + oc0)) * HW + hw] = silu(a20 * s2[oc0] + b2[oc0]);
        bbuf[((size_t)(bi * 32 + oc0 + 1)) * HW + hw] = silu(a21 * s2[oc0 + 1] + b2[oc0 + 1]);
    }
    __syncthreads();
    // m1: wave w computes oc = w (16 oc, 16 waves)
    float accm = 0.f;
    #pragma unroll 8
    for (int ic = 0; ic < 32; ++ic)
        accm += aT[ic][lane] * wtm1[ic * 16 + wv];
    y16[((size_t)(bi * 16 + wv)) * HW + hw] = silu(accm * sm1[wv] + bm1[wv]);
}

// ---------------------------------------------------------------------------
// Kernel 3: m2 (3x3, 16->32, pad 1) + BN + SiLU + residual (a), then cv3
// (1x1 over concat(a', b), 64->64) via LDS tile. block 1024 = 16 waves x
// 64 px. Wave w: oc {2w,2w+1} of m2 (s_load_dwordx2 weights), then
// oc [4w,4w+4) of cv3 (s_load_dwordx4 weights).
// ---------------------------------------------------------------------------
__global__ __launch_bounds__(1024) void m2cv3_kernel(
    const float* __restrict__ y16, const float* __restrict__ a,
    const float* __restrict__ bbuf,
    const float* __restrict__ wtm2, const float* __restrict__ sm2, const float* __restrict__ bm2,
    const float* __restrict__ wtc, const float* __restrict__ sc, const float* __restrict__ bc,
    float* __restrict__ out) {
    __shared__ float a2[32][64];
    const int t = threadIdx.x;
    const int lane = t & 63;
    const int wv = __builtin_amdgcn_readfirstlane(t >> 6);   // 0..15
    const int oc0 = wv * 2;
    const int pix = blockIdx.x * 64 + lane;
    const int bi = pix / HW;
    const int hw = pix - bi * HW;
    const int h = hw / W;
    const int w = hw - h * W;
    const float* yp = y16 + (size_t)(bi * 16) * HW;

    float m0 = 0.f, m1 = 0.f;
    #pragma unroll 2
    for (int ic = 0; ic < 16; ++ic) {
        #pragma unroll
        for (int kh = 0; kh < 3; ++kh) {
            const int rr = h + kh - 1;
            const bool rin = (rr >= 0) && (rr < H);
            #pragma unroll
            for (int kw = 0; kw < 3; ++kw) {
                const int cc = w + kw - 1;
                const bool in = rin && (cc >= 0) && (cc < W);
                const float yv = in ? yp[(size_t)ic * HW + rr * W + cc] : 0.0f;
                const int tap = ic * 9 + kh * 3 + kw;
                m0 += yv * wtm2[tap * 32 + oc0];
                m1 += yv * wtm2[tap * 32 + oc0 + 1];
            }
        }
    }
    a2[oc0][lane] = a[((size_t)(bi * 32 + oc0)) * HW + hw]
                  + silu(m0 * sm2[oc0] + bm2[oc0]);
    a2[oc0 + 1][lane] = a[((size_t)(bi * 32 + oc0 + 1)) * HW + hw]
                      + silu(m1 * sm2[oc0 + 1] + bm2[oc0 + 1]);
    __syncthreads();
    // cv3: wave w computes oc [4w, 4w+4)
    const int oc3 = wv * 4;
    const float* bp = bbuf + (size_t)(bi * 32) * HW + hw;
    float c0 = 0.f, c1 = 0.f, c2 = 0.f, c3 = 0.f;
    #pragma unroll 8
    for (int ic = 0; ic < 32; ++ic) {
        const float av = a2[ic][lane];
        c0 += av * wtc[ic * 64 + oc3];
        c1 += av * wtc[ic * 64 + oc3 + 1];
        c2 += av * wtc[ic * 64 + oc3 + 2];
        c3 += av * wtc[ic * 64 + oc3 + 3];
    }
    #pragma unroll 8
    for (int ic = 0; ic < 32; ++ic) {
        const float bv = bp[(size_t)ic * HW];
        c0 += bv * wtc[(32 + ic) * 64 + oc3];
        c1 += bv * wtc[(32 + ic) * 64 + oc3 + 1];
        c2 += bv * wtc[(32 + ic) * 64 + oc3 + 2];
        c3 += bv * wtc[(32 + ic) * 64 + oc3 + 3];
    }
    out[((size_t)(bi * 64 + oc3)) * HW + hw]     = silu(c0 * sc[oc3]     + bc[oc3]);
    out[((size_t)(bi * 64 + oc3 + 1)) * HW + hw] = silu(c1 * sc[oc3 + 1] + bc[oc3 + 1]);
    out[((size_t)(bi * 64 + oc3 + 2)) * HW + hw] = silu(c2 * sc[oc3 + 2] + bc[oc3 + 2]);
    out[((size_t)(bi * 64 + oc3 + 3)) * HW + hw] = silu(c3 * sc[oc3 + 3] + bc[oc3 + 3]);
}

// ---------------------------------------------------------------------------
extern "C" void kernel_launch(void* const* d_in, const int* in_sizes, int n_in,
                              void* d_out, int out_size, void* d_ws, size_t ws_size,
                              hipStream_t stream) {
    const float* x    = (const float*)d_in[0];
    const float* cv1w = (const float*)d_in[1];
    const float* cv1s = (const float*)d_in[2];
    const float* cv1b = (const float*)d_in[3];
    const float* cv2w = (const float*)d_in[4];
    const float* cv2s = (const float*)d_in[5];
    const float* cv2b = (const float*)d_in[6];
    const float* m1w  = (const float*)d_in[7];
    const float* m1s  = (const float*)d_in[8];
    const float* m1b  = (const float*)d_in[9];
    const float* m2w  = (const float*)d_in[10];
    const float* m2s  = (const float*)d_in[11];
    const float* m2b  = (const float*)d_in[12];
    const float* cv3w = (const float*)d_in[13];
    const float* cv3s = (const float*)d_in[14];
    const float* cv3b = (const float*)d_in[15];

    float* ws   = (float*)d_ws;
    float* g    = ws;                 // 4*4*6400   = 102400 floats
    float* a    = ws + 102400;        // 4*32*6400  = 819200
    float* bbuf = ws + 921600;        // 4*32*6400  = 819200
    float* y16  = ws + 1740800;       // 4*16*6400  = 409600 (end 2150400)
    float* wt1  = ws + 2150400;       // 68*32 = 2176
    float* wt2  = ws + 2152576;       // 2176
    float* wtm1 = ws + 2154752;       // 32*16 = 512
    float* wtm2 = ws + 2155264;       // 144*32 = 4608
    float* wtc  = ws + 2159872;       // 64*64 = 4096 (end 2163968)

    glcm_kernel<<<GLCM_BLOCKS + PACK_BLOCKS, 256, 0, stream>>>(
        x, g, cv1w, cv2w, m1w, m2w, cv3w, wt1, wt2, wtm1, wtm2, wtc);
    stage1_kernel<<<NPIX / 64, 1024, 0, stream>>>(x, g, wt1, cv1s, cv1b,
                                                  wt2, cv2s, cv2b,
                                                  wtm1, m1s, m1b, a, bbuf, y16);
    m2cv3_kernel<<<NPIX / 64, 1024, 0, stream>>>(y16, a, bbuf, wtm2, m2s, m2b,
                                                 wtc, cv3s, cv3b, (float*)d_out);
}

// Round 6
// 61.913 us; speedup vs baseline: 1.3078x; 1.1606x over previous
//
#include <hip/hip_runtime.h>
#include <math.h>

constexpr int B = 4, C = 64, H = 80, W = 80;
constexpr int HW = H * W;            // 6400
constexpr int NPIX = B * HW;         // 25600

typedef unsigned u32;

static __device__ __forceinline__ float silu(float v) {
    float e = __expf(-v);
    return v * __builtin_amdgcn_rcpf(1.0f + e);
}

// ---- packed u16 helpers (both GLCM channels in one instruction) -----------
static __device__ __forceinline__ u32 pks(u32 a, u32 b){u32 d; asm("v_pk_sub_u16 %0,%1,%2":"=v"(d):"v"(a),"v"(b)); return d;}
static __device__ __forceinline__ u32 pka(u32 a, u32 b){u32 d; asm("v_pk_add_u16 %0,%1,%2":"=v"(d):"v"(a),"v"(b)); return d;}
static __device__ __forceinline__ u32 pkm(u32 a, u32 b){u32 d; asm("v_pk_mul_lo_u16 %0,%1,%2":"=v"(d):"v"(a),"v"(b)); return d;}
static __device__ __forceinline__ u32 pkmin(u32 a, u32 b){u32 d; asm("v_pk_min_u16 %0,%1,%2":"=v"(d):"v"(a),"v"(b)); return d;}
static __device__ __forceinline__ u32 pkmaxi(u32 a, u32 b){u32 d; asm("v_pk_max_i16 %0,%1,%2":"=v"(d):"v"(a),"v"(b)); return d;}
static __device__ __forceinline__ float cb0(u32 a){float f; asm("v_cvt_f32_ubyte0 %0,%1":"=v"(f):"v"(a)); return f;}
static __device__ __forceinline__ float cb2(u32 a){float f; asm("v_cvt_f32_ubyte2 %0,%1":"=v"(f):"v"(a)); return f;}

// packed compare-exchange: both u16 halves sorted independently (2 channels)
static __device__ __forceinline__ void ce(u32 &x, u32 &y) {
    u32 mn, mx;
    asm("v_pk_min_u16 %0, %2, %3\n\t"
        "v_pk_max_u16 %1, %2, %3"
        : "=&v"(mn), "=v"(mx) : "v"(x), "v"(y));
    x = mn; y = mx;
}

// ---------------------------------------------------------------------------
// Kernel 1: GLCM features (unchanged from round 5, pack-tail removed).
// thread = (pixel, 2 channels) packed in u16 halves; 256 thr = 8 px x 32 cp.
// ---------------------------------------------------------------------------
__global__ __launch_bounds__(256) void glcm_kernel(const float* __restrict__ x,
                                                   float* __restrict__ g) {
    const int t = threadIdx.x;
    const int pxl = t & 7;               // 0..7
    const int grp = t >> 3;              // 0..31 (channel pair)
    const int pix = blockIdx.x * 8 + pxl;
    const int b = pix / HW;
    const int hw = pix - b * HW;
    const int h = hw / W;
    const int w = hw - h * W;
    const int hm = h > 0 ? h - 1 : 0;
    const int hp = h < H - 1 ? h + 1 : H - 1;
    const int wm = w > 0 ? w - 1 : 0;
    const int wp = w < W - 1 ? w + 1 : W - 1;
    const int o[9] = {hm * W + wm, hm * W + w, hm * W + wp,
                      h  * W + wm, h  * W + w, h  * W + wp,
                      hp * W + wm, hp * W + w, hp * W + wp};
    const float* c0 = x + (size_t)(b * C + grp * 2) * HW;
    const float* c1 = c0 + HW;

    u32 qpk[9];
    #pragma unroll
    for (int k = 0; k < 9; ++k) {
        int a0 = (int)(c0[o[k]] * 7.0f);
        int a1 = (int)(c1[o[k]] * 7.0f);
        a0 = a0 < 0 ? 0 : (a0 > 7 ? 7 : a0);
        a1 = a1 < 0 ? 0 : (a1 > 7 ? 7 : a1);
        qpk[k] = (u32)a0 | ((u32)a1 << 16);
    }

    static constexpr int PA[20] = {0,1,3,4,6,7, 0,1,2,3,4,5, 0,1,3,4, 1,2,4,5};
    static constexpr int PB[20] = {1,2,4,5,7,8, 3,4,5,6,7,8, 4,5,7,8, 3,4,6,7};

    const u32 ONEpk = 0x00010001u, EIGHTpk = 0x00080008u;
    u32 cs = 0;                 // packed sum of d^2 per half (<=980)
    float hsum = 0.f;
    u32 key[20];
    #pragma unroll
    for (int a = 0; a < 20; ++a) {
        const u32 qa = qpk[PA[a]], qb = qpk[PB[a]];
        const u32 d = pks(qa, qb);                 // i16 wrap-safe
        cs = pka(cs, pkm(d, d));
        const u32 ad = pkmaxi(d, pks(0u, d));      // |d| per half 0..7
        const u32 h1 = pka(ad, ONEpk);             // 1..8, bytes 0 and 2
        hsum += __builtin_amdgcn_rcpf(cb0(h1)) + __builtin_amdgcn_rcpf(cb2(h1));
        key[a] = pka(pkm(qa, EIGHTpk), qb);        // qa*8+qb per half, <=63
    }

    // Batcher odd-even mergesort for n=32, pruned to the low 20 slots
    #pragma unroll
    for (int p = 1; p < 32; p <<= 1) {
        #pragma unroll
        for (int k = p; k >= 1; k >>= 1) {
            const int jm = k % p;
            #pragma unroll
            for (int lo = 0; lo < 20; ++lo) {
                const int hi = lo + k;
                if (hi < 20 && lo >= jm && ((lo - jm) % (2 * k)) < k &&
                    (lo / (2 * p)) == (hi / (2 * p))) {
                    ce(key[lo], key[hi]);
                }
            }
        }
    }

    // boundary flags: eq[a] = (key[a]==key[a-1]) per half as 0/1 (packed)
    u32 eq[20];
    #pragma unroll
    for (int a = 1; a < 20; ++a)
        eq[a] = pks(ONEpk, pkmin(pks(key[a], key[a - 1]), ONEpk));

    // forward run scan: pc = (pc+1)*eq  (packed), psum += pc
    u32 pc = 0, ps = 0, pv[20];
    pv[0] = 0;
    #pragma unroll
    for (int a = 1; a < 20; ++a) {
        pc = pkm(pka(pc, ONEpk), eq[a]);
        pv[a] = pc;
        ps = pka(ps, pc);
    }
    // backward run scan + multiplicity product: m = p + r + 1 (<=20, byte)
    float pr0, pr1;
    {
        const u32 m = pka(pv[19], ONEpk);
        pr0 = cb0(m); pr1 = cb2(m);
    }
    u32 rc = 0;
    #pragma unroll
    for (int a = 18; a >= 0; --a) {
        rc = pkm(pka(rc, ONEpk), eq[a + 1]);
        const u32 m = pka(pka(pv[a], rc), ONEpk);
        pr0 *= cb0(m); pr1 *= cb2(m);
    }

    const int csum = (int)(cs & 0xFFFFu) + (int)(cs >> 16);
    const int psum = (int)(ps & 0xFFFFu) + (int)(ps >> 16);
    const float lsum = __logf(pr0) + __logf(pr1);

    float fc = (float)csum * (1.f / 20.f);
    float fe = ((float)psum * 2.f + 40.f) * (1.f / 400.f);
    float fn = -(lsum + 40.f * -2.9957322736f /*log(0.05)*/) * (1.f / 20.f);
    float fh = hsum * (1.f / 20.f);

    // reduce over 8 channel-pairs within the wave (lane bits 3..5)
    #pragma unroll
    for (int m = 8; m < 64; m <<= 1) {
        fc += __shfl_xor(fc, m);
        fe += __shfl_xor(fe, m);
        fn += __shfl_xor(fn, m);
        fh += __shfl_xor(fh, m);
    }
    __shared__ float red[4][8][4];
    const int wv = t >> 6;
    if ((t & 63) < 8) {
        red[wv][pxl][0] = fc; red[wv][pxl][1] = fe;
        red[wv][pxl][2] = fn; red[wv][pxl][3] = fh;
    }
    __syncthreads();
    if (t < 32) {
        const int p2 = t >> 2, f = t & 3;
        float s = red[0][p2][f] + red[1][p2][f] + red[2][p2][f] + red[3][p2][f];
        s *= (1.f / 64.f);
        const int pix2 = blockIdx.x * 8 + p2;
        const int b2 = pix2 / HW;
        const int hw2 = pix2 - b2 * HW;
        g[((size_t)(b2 * 4 + f)) * HW + hw2] = s;
    }
}

// ---------------------------------------------------------------------------
// Kernel 2: cv1 + cv2 (1x1, 68->32) + BN + SiLU, then m1 (1x1, 32->16).
// block 512 = 8 waves x 64 px. KEY FIX vs r5: activations (x,g tile) staged
// into LDS ONCE per block (8.5 coalesced rounds), waves FMA from LDS —
// global load instrs per block drop 1088 -> 72 (kernels were load-latency
// bound, not VALU bound: r4 VALUBusy 14%). Weights stay in original oc-major
// layout (contiguous per oc -> batched wave-uniform s_loads).
// Wave w: 4 oc of cv1 AND cv2; then 2 oc of m1 via aT LDS tile.
// ---------------------------------------------------------------------------
__global__ __launch_bounds__(512) void stage1_kernel(
    const float* __restrict__ x, const float* __restrict__ g,
    const float* __restrict__ w1, const float* __restrict__ s1, const float* __restrict__ b1,
    const float* __restrict__ w2, const float* __restrict__ s2, const float* __restrict__ b2,
    const float* __restrict__ wm1, const float* __restrict__ sm1, const float* __restrict__ bm1,
    float* __restrict__ a, float* __restrict__ bbuf, float* __restrict__ y16) {
    __shared__ float xg[68][64];   // 17.4 KB: 64 x-ch + 4 g-ch for 64 px
    __shared__ float aT[32][64];   // 8 KB: cv1 output tile for m1
    const int t = threadIdx.x;
    const int p0 = blockIdx.x * 64;
    const int bi = p0 / HW;
    const int hw0 = p0 - bi * HW;

    const float* xb = x + (size_t)(bi * C) * HW + hw0;
    const float* gb = g + (size_t)(bi * 4) * HW + hw0;
    #pragma unroll
    for (int rnd = 0; rnd < 9; ++rnd) {
        const int e = rnd * 512 + t;
        if (e < 68 * 64) {
            const int ic = e >> 6, px = e & 63;
            xg[ic][px] = (ic < 64) ? xb[(size_t)ic * HW + px]
                                   : gb[(size_t)(ic - 64) * HW + px];
        }
    }
    __syncthreads();

    const int lane = t & 63;
    const int wv = __builtin_amdgcn_readfirstlane(t >> 6);   // 0..7
    const int oc0 = wv * 4;
    const int hw = hw0 + lane;

    float acc1[4] = {0.f, 0.f, 0.f, 0.f};
    float acc2[4] = {0.f, 0.f, 0.f, 0.f};
    #pragma unroll 4
    for (int ic = 0; ic < 68; ++ic) {
        const float v = xg[ic][lane];
        #pragma unroll
        for (int j = 0; j < 4; ++j) {
            acc1[j] += v * w1[(oc0 + j) * 68 + ic];
            acc2[j] += v * w2[(oc0 + j) * 68 + ic];
        }
    }
    #pragma unroll
    for (int j = 0; j < 4; ++j) {
        const int oc = oc0 + j;
        const float v1 = silu(acc1[j] * s1[oc] + b1[oc]);
        a[((size_t)(bi * 32 + oc)) * HW + hw] = v1;
        aT[oc][lane] = v1;
        bbuf[((size_t)(bi * 32 + oc)) * HW + hw] = silu(acc2[j] * s2[oc] + b2[oc]);
    }
    __syncthreads();
    // m1: wave w -> oc {2w, 2w+1}
    const int om0 = wv * 2;
    float am0 = 0.f, am1 = 0.f;
    #pragma unroll 4
    for (int ic = 0; ic < 32; ++ic) {
        const float v = aT[ic][lane];
        am0 += v * wm1[om0 * 32 + ic];
        am1 += v * wm1[(om0 + 1) * 32 + ic];
    }
    y16[((size_t)(bi * 16 + om0)) * HW + hw]     = silu(am0 * sm1[om0] + bm1[om0]);
    y16[((size_t)(bi * 16 + om0 + 1)) * HW + hw] = silu(am1 * sm1[om0 + 1] + bm1[om0 + 1]);
}

// ---------------------------------------------------------------------------
// Kernel 3: m2 (3x3, 16->32, pad 1) + BN + SiLU + residual, then cv3
// (1x1, 64->64). block 512 = 8 waves x 64 px. y16 staged in LDS with full
// halo as 4 zero-padded rows ys[16][4][82] (branchless taps); bbuf staged
// too. Wave w: 4 oc of m2 -> a2 tile; then 8 oc of cv3.
// ---------------------------------------------------------------------------
__global__ __launch_bounds__(512) void m2cv3_kernel(
    const float* __restrict__ y16, const float* __restrict__ a,
    const float* __restrict__ bbuf,
    const float* __restrict__ wm2, const float* __restrict__ sm2, const float* __restrict__ bm2,
    const float* __restrict__ wc, const float* __restrict__ sc, const float* __restrict__ bc,
    float* __restrict__ out) {
    __shared__ float ys[16][4][82];  // 21 KB: rows h0-1..h0+2, cols -1..80
    __shared__ float a2[32][64];     // 8 KB
    __shared__ float bs[32][64];     // 8 KB
    const int t = threadIdx.x;
    const int p0 = blockIdx.x * 64;
    const int bi = p0 / HW;
    const int hw0 = p0 - bi * HW;
    const int h0 = hw0 / W;

    // stage y16 halo (zero outside image -> zero-pad semantics of m2)
    const float* yb = y16 + (size_t)(bi * 16) * HW;
    for (int e = t; e < 16 * 4 * 82; e += 512) {
        const int ch = e / 328;
        const int rem = e - ch * 328;
        const int row = rem / 82;
        const int col = rem - row * 82;
        const int r = h0 - 1 + row;
        const int c = col - 1;
        float v = 0.f;
        if ((unsigned)r < (unsigned)H && (unsigned)c < (unsigned)W)
            v = yb[(size_t)ch * HW + r * W + c];
        ys[ch][row][col] = v;
    }
    // stage bbuf tile
    for (int e = t; e < 32 * 64; e += 512) {
        const int ic = e >> 6, px = e & 63;
        bs[ic][px] = bbuf[((size_t)(bi * 32 + ic)) * HW + hw0 + px];
    }
    __syncthreads();

    const int lane = t & 63;
    const int wv = __builtin_amdgcn_readfirstlane(t >> 6);   // 0..7
    const int hw = hw0 + lane;
    const int h = hw / W;
    const int w = hw - h * W;
    const int lr = h - h0;           // 0 or 1 (tile spans <= 2 rows)
    const int oc0 = wv * 4;

    float acc[4] = {0.f, 0.f, 0.f, 0.f};
    #pragma unroll 2
    for (int ic = 0; ic < 16; ++ic) {
        #pragma unroll
        for (int ky = 0; ky < 3; ++ky) {
            #pragma unroll
            for (int kx = 0; kx < 3; ++kx) {
                const float v = ys[ic][lr + ky][w + kx];
                const int tap = ic * 9 + ky * 3 + kx;
                #pragma unroll
                for (int j = 0; j < 4; ++j)
                    acc[j] += v * wm2[(oc0 + j) * 144 + tap];
            }
        }
    }
    #pragma unroll
    for (int j = 0; j < 4; ++j) {
        const int oc = oc0 + j;
        a2[oc][lane] = a[((size_t)(bi * 32 + oc)) * HW + hw]
                     + silu(acc[j] * sm2[oc] + bm2[oc]);
    }
    __syncthreads();
    // cv3: wave w -> oc [8w, 8w+8)
    const int oc3 = wv * 8;
    float c_[8] = {0.f, 0.f, 0.f, 0.f, 0.f, 0.f, 0.f, 0.f};
    #pragma unroll 4
    for (int ic = 0; ic < 32; ++ic) {
        const float av = a2[ic][lane];
        const float bv = bs[ic][lane];
        #pragma unroll
        for (int j = 0; j < 8; ++j) {
            c_[j] += av * wc[(oc3 + j) * 64 + ic];
            c_[j] += bv * wc[(oc3 + j) * 64 + 32 + ic];
        }
    }
    #pragma unroll
    for (int j = 0; j < 8; ++j) {
        const int oc = oc3 + j;
        out[((size_t)(bi * 64 + oc)) * HW + hw] = silu(c_[j] * sc[oc] + bc[oc]);
    }
}

// ---------------------------------------------------------------------------
extern "C" void kernel_launch(void* const* d_in, const int* in_sizes, int n_in,
                              void* d_out, int out_size, void* d_ws, size_t ws_size,
                              hipStream_t stream) {
    const float* x    = (const float*)d_in[0];
    const float* cv1w = (const float*)d_in[1];
    const float* cv1s = (const float*)d_in[2];
    const float* cv1b = (const float*)d_in[3];
    const float* cv2w = (const float*)d_in[4];
    const float* cv2s = (const float*)d_in[5];
    const float* cv2b = (const float*)d_in[6];
    const float* m1w  = (const float*)d_in[7];
    const float* m1s  = (const float*)d_in[8];
    const float* m1b  = (const float*)d_in[9];
    const float* m2w  = (const float*)d_in[10];
    const float* m2s  = (const float*)d_in[11];
    const float* m2b  = (const float*)d_in[12];
    const float* cv3w = (const float*)d_in[13];
    const float* cv3s = (const float*)d_in[14];
    const float* cv3b = (const float*)d_in[15];

    float* ws   = (float*)d_ws;
    float* g    = ws;                 // 4*4*6400   = 102400 floats
    float* a    = ws + 102400;        // 4*32*6400  = 819200
    float* bbuf = ws + 921600;        // 4*32*6400  = 819200
    float* y16  = ws + 1740800;       // 4*16*6400  = 409600 (end 2150400)

    glcm_kernel<<<NPIX / 8, 256, 0, stream>>>(x, g);
    stage1_kernel<<<NPIX / 64, 512, 0, stream>>>(x, g, cv1w, cv1s, cv1b,
                                                 cv2w, cv2s, cv2b,
                                                 m1w, m1s, m1b, a, bbuf, y16);
    m2cv3_kernel<<<NPIX / 64, 512, 0, stream>>>(y16, a, bbuf, m2w, m2s, m2b,
                                                cv3w, cv3s, cv3b, (float*)d_out);
}

// Round 7
// 61.353 us; speedup vs baseline: 1.3197x; 1.0091x over previous
//
#include <hip/hip_runtime.h>
#include <math.h>

constexpr int B = 4, C = 64, H = 80, W = 80;
constexpr int HW = H * W;            // 6400
constexpr int NPIX = B * HW;         // 25600

typedef unsigned u32;

static __device__ __forceinline__ float silu(float v) {
    float e = __expf(-v);
    return v * __builtin_amdgcn_rcpf(1.0f + e);
}

// ---- packed u16 helpers (both GLCM channels in one instruction) -----------
static __device__ __forceinline__ u32 pks(u32 a, u32 b){u32 d; asm("v_pk_sub_u16 %0,%1,%2":"=v"(d):"v"(a),"v"(b)); return d;}
static __device__ __forceinline__ u32 pka(u32 a, u32 b){u32 d; asm("v_pk_add_u16 %0,%1,%2":"=v"(d):"v"(a),"v"(b)); return d;}
static __device__ __forceinline__ u32 pkm(u32 a, u32 b){u32 d; asm("v_pk_mul_lo_u16 %0,%1,%2":"=v"(d):"v"(a),"v"(b)); return d;}
static __device__ __forceinline__ u32 pkmin(u32 a, u32 b){u32 d; asm("v_pk_min_u16 %0,%1,%2":"=v"(d):"v"(a),"v"(b)); return d;}
static __device__ __forceinline__ u32 pkmaxi(u32 a, u32 b){u32 d; asm("v_pk_max_i16 %0,%1,%2":"=v"(d):"v"(a),"v"(b)); return d;}
static __device__ __forceinline__ float cb0(u32 a){float f; asm("v_cvt_f32_ubyte0 %0,%1":"=v"(f):"v"(a)); return f;}
static __device__ __forceinline__ float cb2(u32 a){float f; asm("v_cvt_f32_ubyte2 %0,%1":"=v"(f):"v"(a)); return f;}

// packed compare-exchange: both u16 halves sorted independently (2 channels)
static __device__ __forceinline__ void ce(u32 &x, u32 &y) {
    u32 mn, mx;
    asm("v_pk_min_u16 %0, %2, %3\n\t"
        "v_pk_max_u16 %1, %2, %3"
        : "=&v"(mn), "=v"(mx) : "v"(x), "v"(y));
    x = mn; y = mx;
}

// ---------------------------------------------------------------------------
// Kernel 1: GLCM + cv1 + cv2 + m1 fused (stage1 needs only its own tile's
// pixels -> no device sync). block 256 = 8 px x 32 ch-pairs, re-mapped to
// 8 px x 32 oc (cv1/cv2) and 8 px x 16 oc (m1). g and x-centers stay in LDS.
// ---------------------------------------------------------------------------
__global__ __launch_bounds__(256) void glcm_stage1_kernel(
    const float* __restrict__ x,
    const float* __restrict__ w1, const float* __restrict__ s1, const float* __restrict__ b1,
    const float* __restrict__ w2, const float* __restrict__ s2, const float* __restrict__ b2,
    const float* __restrict__ wm1, const float* __restrict__ sm1, const float* __restrict__ bm1,
    float* __restrict__ a, float* __restrict__ bbuf, float* __restrict__ y16) {
    __shared__ float ws1T[68 * 33];   // [ic][oc], pad 33 -> bank-spread
    __shared__ float ws2T[68 * 33];
    __shared__ float wsm1T[32 * 17];  // [ic][oc16], pad 17
    __shared__ float xs[68][8];       // x centers (64 ch) + g features (4)
    __shared__ float aT[32][8];       // cv1 output tile for m1
    __shared__ float red[4][8][4];

    const int t = threadIdx.x;

    // ---- phase 0: stage weights into LDS (transposed, padded) ----
    {
        const int oc = t >> 3, i0 = t & 7;
        for (int ic = i0; ic < 68; ic += 8) {
            ws1T[ic * 33 + oc] = w1[oc * 68 + ic];
            ws2T[ic * 33 + oc] = w2[oc * 68 + ic];
        }
        if (oc < 16)
            for (int ic = i0; ic < 32; ic += 8)
                wsm1T[ic * 17 + oc] = wm1[oc * 32 + ic];
    }

    // ---- phase 1: GLCM (core identical to round 6) ----
    const int pxl = t & 7;               // 0..7
    const int grp = t >> 3;              // 0..31 (channel pair)
    const int pix = blockIdx.x * 8 + pxl;
    const int b = pix / HW;
    const int hw = pix - b * HW;
    const int h = hw / W;
    const int w = hw - h * W;
    const int hm = h > 0 ? h - 1 : 0;
    const int hp = h < H - 1 ? h + 1 : H - 1;
    const int wm = w > 0 ? w - 1 : 0;
    const int wp = w < W - 1 ? w + 1 : W - 1;
    const int o[9] = {hm * W + wm, hm * W + w, hm * W + wp,
                      h  * W + wm, h  * W + w, h  * W + wp,
                      hp * W + wm, hp * W + w, hp * W + wp};
    const float* c0 = x + (size_t)(b * C + grp * 2) * HW;
    const float* c1 = c0 + HW;

    u32 qpk[9];
    #pragma unroll
    for (int k = 0; k < 9; ++k) {
        const float v0 = c0[o[k]];
        const float v1 = c1[o[k]];
        if (k == 4) {                     // park raw centers for stage1
            xs[grp * 2][pxl] = v0;
            xs[grp * 2 + 1][pxl] = v1;
        }
        int a0 = (int)(v0 * 7.0f);
        int a1 = (int)(v1 * 7.0f);
        a0 = a0 < 0 ? 0 : (a0 > 7 ? 7 : a0);
        a1 = a1 < 0 ? 0 : (a1 > 7 ? 7 : a1);
        qpk[k] = (u32)a0 | ((u32)a1 << 16);
    }

    static constexpr int PA[20] = {0,1,3,4,6,7, 0,1,2,3,4,5, 0,1,3,4, 1,2,4,5};
    static constexpr int PB[20] = {1,2,4,5,7,8, 3,4,5,6,7,8, 4,5,7,8, 3,4,6,7};

    const u32 ONEpk = 0x00010001u, EIGHTpk = 0x00080008u;
    u32 cs = 0;
    float hsum = 0.f;
    u32 key[20];
    #pragma unroll
    for (int ai = 0; ai < 20; ++ai) {
        const u32 qa = qpk[PA[ai]], qb = qpk[PB[ai]];
        const u32 d = pks(qa, qb);
        cs = pka(cs, pkm(d, d));
        const u32 ad = pkmaxi(d, pks(0u, d));
        const u32 h1 = pka(ad, ONEpk);
        hsum += __builtin_amdgcn_rcpf(cb0(h1)) + __builtin_amdgcn_rcpf(cb2(h1));
        key[ai] = pka(pkm(qa, EIGHTpk), qb);
    }

    // Batcher odd-even mergesort for n=32, pruned to the low 20 slots
    #pragma unroll
    for (int p = 1; p < 32; p <<= 1) {
        #pragma unroll
        for (int k = p; k >= 1; k >>= 1) {
            const int jm = k % p;
            #pragma unroll
            for (int lo = 0; lo < 20; ++lo) {
                const int hi = lo + k;
                if (hi < 20 && lo >= jm && ((lo - jm) % (2 * k)) < k &&
                    (lo / (2 * p)) == (hi / (2 * p))) {
                    ce(key[lo], key[hi]);
                }
            }
        }
    }

    u32 eq[20];
    #pragma unroll
    for (int ai = 1; ai < 20; ++ai)
        eq[ai] = pks(ONEpk, pkmin(pks(key[ai], key[ai - 1]), ONEpk));

    u32 pc = 0, ps = 0, pv[20];
    pv[0] = 0;
    #pragma unroll
    for (int ai = 1; ai < 20; ++ai) {
        pc = pkm(pka(pc, ONEpk), eq[ai]);
        pv[ai] = pc;
        ps = pka(ps, pc);
    }
    float pr0, pr1;
    {
        const u32 m = pka(pv[19], ONEpk);
        pr0 = cb0(m); pr1 = cb2(m);
    }
    u32 rc = 0;
    #pragma unroll
    for (int ai = 18; ai >= 0; --ai) {
        rc = pkm(pka(rc, ONEpk), eq[ai + 1]);
        const u32 m = pka(pka(pv[ai], rc), ONEpk);
        pr0 *= cb0(m); pr1 *= cb2(m);
    }

    const int csum = (int)(cs & 0xFFFFu) + (int)(cs >> 16);
    const int psum = (int)(ps & 0xFFFFu) + (int)(ps >> 16);
    const float lsum = __logf(pr0) + __logf(pr1);

    float fc = (float)csum * (1.f / 20.f);
    float fe = ((float)psum * 2.f + 40.f) * (1.f / 400.f);
    float fn = -(lsum + 40.f * -2.9957322736f) * (1.f / 20.f);
    float fh = hsum * (1.f / 20.f);

    #pragma unroll
    for (int m = 8; m < 64; m <<= 1) {
        fc += __shfl_xor(fc, m);
        fe += __shfl_xor(fe, m);
        fn += __shfl_xor(fn, m);
        fh += __shfl_xor(fh, m);
    }
    const int wv = t >> 6;
    if ((t & 63) < 8) {
        red[wv][pxl][0] = fc; red[wv][pxl][1] = fe;
        red[wv][pxl][2] = fn; red[wv][pxl][3] = fh;
    }
    __syncthreads();
    if (t < 32) {
        const int p2 = t >> 2, f = t & 3;
        float s = red[0][p2][f] + red[1][p2][f] + red[2][p2][f] + red[3][p2][f];
        xs[64 + f][p2] = s * (1.f / 64.f);   // g stays in LDS
    }
    __syncthreads();   // xs (centers + g) and staged weights complete

    // ---- phase 2: cv1 + cv2, thread = (px, oc) ----
    {
        const int px = t & 7;
        const int oc = t >> 3;               // 0..31
        float acc1 = 0.f, acc2 = 0.f;
        #pragma unroll 4
        for (int ic = 0; ic < 68; ++ic) {
            const float v = xs[ic][px];
            acc1 += v * ws1T[ic * 33 + oc];
            acc2 += v * ws2T[ic * 33 + oc];
        }
        const int pix2 = blockIdx.x * 8 + px;
        const int bb = pix2 / HW;
        const int hw2 = pix2 - bb * HW;
        const float v1 = silu(acc1 * s1[oc] + b1[oc]);
        a[((size_t)(bb * 32 + oc)) * HW + hw2] = v1;
        aT[oc][px] = v1;
        bbuf[((size_t)(bb * 32 + oc)) * HW + hw2] = silu(acc2 * s2[oc] + b2[oc]);
    }
    __syncthreads();

    // ---- phase 3: m1, thread = (px, oc16), first 128 threads ----
    if (t < 128) {
        const int px = t & 7;
        const int oc = t >> 3;               // 0..15
        float acc = 0.f;
        #pragma unroll 4
        for (int ic = 0; ic < 32; ++ic)
            acc += aT[ic][px] * wsm1T[ic * 17 + oc];
        const int pix2 = blockIdx.x * 8 + px;
        const int bb = pix2 / HW;
        const int hw2 = pix2 - bb * HW;
        y16[((size_t)(bb * 16 + oc)) * HW + hw2] = silu(acc * sm1[oc] + bm1[oc]);
    }
}

// ---------------------------------------------------------------------------
// Kernel 2: m2 (3x3, 16->32, pad 1) + BN + SiLU + residual, then cv3
// (1x1, 64->64). Unchanged from round 6. block 512 = 8 waves x 64 px.
// ---------------------------------------------------------------------------
__global__ __launch_bounds__(512) void m2cv3_kernel(
    const float* __restrict__ y16, const float* __restrict__ a,
    const float* __restrict__ bbuf,
    const float* __restrict__ wm2, const float* __restrict__ sm2, const float* __restrict__ bm2,
    const float* __restrict__ wc, const float* __restrict__ sc, const float* __restrict__ bc,
    float* __restrict__ out) {
    __shared__ float ys[16][4][82];
    __shared__ float a2[32][64];
    __shared__ float bs[32][64];
    const int t = threadIdx.x;
    const int p0 = blockIdx.x * 64;
    const int bi = p0 / HW;
    const int hw0 = p0 - bi * HW;
    const int h0 = hw0 / W;

    const float* yb = y16 + (size_t)(bi * 16) * HW;
    for (int e = t; e < 16 * 4 * 82; e += 512) {
        const int ch = e / 328;
        const int rem = e - ch * 328;
        const int row = rem / 82;
        const int col = rem - row * 82;
        const int r = h0 - 1 + row;
        const int c = col - 1;
        float v = 0.f;
        if ((unsigned)r < (unsigned)H && (unsigned)c < (unsigned)W)
            v = yb[(size_t)ch * HW + r * W + c];
        ys[ch][row][col] = v;
    }
    for (int e = t; e < 32 * 64; e += 512) {
        const int ic = e >> 6, px = e & 63;
        bs[ic][px] = bbuf[((size_t)(bi * 32 + ic)) * HW + hw0 + px];
    }
    __syncthreads();

    const int lane = t & 63;
    const int wv = __builtin_amdgcn_readfirstlane(t >> 6);
    const int hw = hw0 + lane;
    const int h = hw / W;
    const int w = hw - h * W;
    const int lr = h - h0;
    const int oc0 = wv * 4;

    float acc[4] = {0.f, 0.f, 0.f, 0.f};
    #pragma unroll 2
    for (int ic = 0; ic < 16; ++ic) {
        #pragma unroll
        for (int ky = 0; ky < 3; ++ky) {
            #pragma unroll
            for (int kx = 0; kx < 3; ++kx) {
                const float v = ys[ic][lr + ky][w + kx];
                const int tap = ic * 9 + ky * 3 + kx;
                #pragma unroll
                for (int j = 0; j < 4; ++j)
                    acc[j] += v * wm2[(oc0 + j) * 144 + tap];
            }
        }
    }
    #pragma unroll
    for (int j = 0; j < 4; ++j) {
        const int oc = oc0 + j;
        a2[oc][lane] = a[((size_t)(bi * 32 + oc)) * HW + hw]
                     + silu(acc[j] * sm2[oc] + bm2[oc]);
    }
    __syncthreads();
    const int oc3 = wv * 8;
    float c_[8] = {0.f, 0.f, 0.f, 0.f, 0.f, 0.f, 0.f, 0.f};
    #pragma unroll 4
    for (int ic = 0; ic < 32; ++ic) {
        const float av = a2[ic][lane];
        const float bv = bs[ic][lane];
        #pragma unroll
        for (int j = 0; j < 8; ++j) {
            c_[j] += av * wc[(oc3 + j) * 64 + ic];
            c_[j] += bv * wc[(oc3 + j) * 64 + 32 + ic];
        }
    }
    #pragma unroll
    for (int j = 0; j < 8; ++j) {
        const int oc = oc3 + j;
        out[((size_t)(bi * 64 + oc)) * HW + hw] = silu(c_[j] * sc[oc] + bc[oc]);
    }
}

// ---------------------------------------------------------------------------
extern "C" void kernel_launch(void* const* d_in, const int* in_sizes, int n_in,
                              void* d_out, int out_size, void* d_ws, size_t ws_size,
                              hipStream_t stream) {
    const float* x    = (const float*)d_in[0];
    const float* cv1w = (const float*)d_in[1];
    const float* cv1s = (const float*)d_in[2];
    const float* cv1b = (const float*)d_in[3];
    const float* cv2w = (const float*)d_in[4];
    const float* cv2s = (const float*)d_in[5];
    const float* cv2b = (const float*)d_in[6];
    const float* m1w  = (const float*)d_in[7];
    const float* m1s  = (const float*)d_in[8];
    const float* m1b  = (const float*)d_in[9];
    const float* m2w  = (const float*)d_in[10];
    const float* m2s  = (const float*)d_in[11];
    const float* m2b  = (const float*)d_in[12];
    const float* cv3w = (const float*)d_in[13];
    const float* cv3s = (const float*)d_in[14];
    const float* cv3b = (const float*)d_in[15];

    float* ws   = (float*)d_ws;
    float* a    = ws;                 // 4*32*6400 = 819200
    float* bbuf = ws + 819200;        // 819200
    float* y16  = ws + 1638400;       // 409600 (end 2048000)

    glcm_stage1_kernel<<<NPIX / 8, 256, 0, stream>>>(
        x, cv1w, cv1s, cv1b, cv2w, cv2s, cv2b, m1w, m1s, m1b, a, bbuf, y16);
    m2cv3_kernel<<<NPIX / 64, 512, 0, stream>>>(y16, a, bbuf, m2w, m2s, m2b,
                                                cv3w, cv3s, cv3b, (float*)d_out);
}

// Round 8
// 60.199 us; speedup vs baseline: 1.3450x; 1.0192x over previous
//
#include <hip/hip_runtime.h>
#include <math.h>

constexpr int B = 4, C = 64, H = 80, W = 80;
constexpr int HW = H * W;            // 6400
constexpr int NPIX = B * HW;         // 25600
constexpr int PXB = 16;              // pixels per block (16 | W=80)

typedef unsigned u32;

static __device__ __forceinline__ float silu(float v) {
    float e = __expf(-v);
    return v * __builtin_amdgcn_rcpf(1.0f + e);
}

// ---- packed u16 helpers (both GLCM channels in one instruction) -----------
static __device__ __forceinline__ u32 pks(u32 a, u32 b){u32 d; asm("v_pk_sub_u16 %0,%1,%2":"=v"(d):"v"(a),"v"(b)); return d;}
static __device__ __forceinline__ u32 pka(u32 a, u32 b){u32 d; asm("v_pk_add_u16 %0,%1,%2":"=v"(d):"v"(a),"v"(b)); return d;}
static __device__ __forceinline__ u32 pkm(u32 a, u32 b){u32 d; asm("v_pk_mul_lo_u16 %0,%1,%2":"=v"(d):"v"(a),"v"(b)); return d;}
static __device__ __forceinline__ u32 pkmin(u32 a, u32 b){u32 d; asm("v_pk_min_u16 %0,%1,%2":"=v"(d):"v"(a),"v"(b)); return d;}
static __device__ __forceinline__ u32 pkmaxi(u32 a, u32 b){u32 d; asm("v_pk_max_i16 %0,%1,%2":"=v"(d):"v"(a),"v"(b)); return d;}
static __device__ __forceinline__ float cb0(u32 a){float f; asm("v_cvt_f32_ubyte0 %0,%1":"=v"(f):"v"(a)); return f;}
static __device__ __forceinline__ float cb2(u32 a){float f; asm("v_cvt_f32_ubyte2 %0,%1":"=v"(f):"v"(a)); return f;}

// packed compare-exchange: both u16 halves sorted independently (2 channels)
static __device__ __forceinline__ void ce(u32 &x, u32 &y) {
    u32 mn, mx;
    asm("v_pk_min_u16 %0, %2, %3\n\t"
        "v_pk_max_u16 %1, %2, %3"
        : "=&v"(mn), "=v"(mx) : "v"(x), "v"(y));
    x = mn; y = mx;
}

// ---------------------------------------------------------------------------
// Kernel 1: GLCM + cv1 + cv2 + m1 fused. block 512 = 16 px x 32 ch-pairs,
// re-mapped to 16 px x 32 oc (cv1/cv2) and 16 px x 16 oc (m1).
// R7 lesson: VGPR_Count=40 (no waves-floor declared) register-starved the
// sort/scan code (~2.6x instr bloat). __launch_bounds__(512,4) -> cap 128.
// 16-px blocks also make every stencil load a full 64B line and halve the
// per-pixel weight-staging cost.
// ---------------------------------------------------------------------------
__global__ __launch_bounds__(512, 4) void glcm_stage1_kernel(
    const float* __restrict__ x,
    const float* __restrict__ w1, const float* __restrict__ s1, const float* __restrict__ b1,
    const float* __restrict__ w2, const float* __restrict__ s2, const float* __restrict__ b2,
    const float* __restrict__ wm1, const float* __restrict__ sm1, const float* __restrict__ bm1,
    float* __restrict__ a, float* __restrict__ bbuf, float* __restrict__ y16) {
    __shared__ float ws1T[68 * 33];   // [ic][oc], pad 33 -> bank-spread
    __shared__ float ws2T[68 * 33];
    __shared__ float wsm1T[32 * 17];  // [ic][oc16], pad 17
    __shared__ float xs[68][PXB];     // x centers (64 ch) + g features (4)
    __shared__ float aT[32][PXB];     // cv1 output tile for m1
    __shared__ float red[8][PXB][4];

    const int t = threadIdx.x;

    // ---- phase 0: stage weights into LDS (transposed, padded) ----
    {
        const int oc = t >> 4, i0 = t & 15;
        #pragma unroll
        for (int ic = i0; ic < 68; ic += 16) {
            ws1T[ic * 33 + oc] = w1[oc * 68 + ic];
            ws2T[ic * 33 + oc] = w2[oc * 68 + ic];
        }
        if (oc < 16) {
            wsm1T[i0 * 17 + oc]        = wm1[oc * 32 + i0];
            wsm1T[(i0 + 16) * 17 + oc] = wm1[oc * 32 + i0 + 16];
        }
    }

    // ---- phase 1: GLCM (packed-u16 core, math identical to R6/R7) ----
    const int pxl = t & 15;              // 0..15
    const int grp = t >> 4;              // 0..31 (channel pair)
    const int pix = blockIdx.x * PXB + pxl;
    const int b = pix / HW;
    const int hw = pix - b * HW;
    const int h = hw / W;
    const int w = hw - h * W;
    const int hm = h > 0 ? h - 1 : 0;
    const int hp = h < H - 1 ? h + 1 : H - 1;
    const int wm = w > 0 ? w - 1 : 0;
    const int wp = w < W - 1 ? w + 1 : W - 1;
    const int o[9] = {hm * W + wm, hm * W + w, hm * W + wp,
                      h  * W + wm, h  * W + w, h  * W + wp,
                      hp * W + wm, hp * W + w, hp * W + wp};
    const float* c0 = x + (size_t)(b * C + grp * 2) * HW;
    const float* c1 = c0 + HW;

    u32 qpk[9];
    #pragma unroll
    for (int k = 0; k < 9; ++k) {
        const float v0 = c0[o[k]];
        const float v1 = c1[o[k]];
        if (k == 4) {                     // park raw centers for stage1
            xs[grp * 2][pxl] = v0;
            xs[grp * 2 + 1][pxl] = v1;
        }
        int a0 = (int)(v0 * 7.0f);
        int a1 = (int)(v1 * 7.0f);
        a0 = a0 < 0 ? 0 : (a0 > 7 ? 7 : a0);
        a1 = a1 < 0 ? 0 : (a1 > 7 ? 7 : a1);
        qpk[k] = (u32)a0 | ((u32)a1 << 16);
    }

    static constexpr int PA[20] = {0,1,3,4,6,7, 0,1,2,3,4,5, 0,1,3,4, 1,2,4,5};
    static constexpr int PB[20] = {1,2,4,5,7,8, 3,4,5,6,7,8, 4,5,7,8, 3,4,6,7};

    const u32 ONEpk = 0x00010001u, EIGHTpk = 0x00080008u;
    u32 cs = 0;
    float hsum = 0.f;
    u32 key[20];
    #pragma unroll
    for (int ai = 0; ai < 20; ++ai) {
        const u32 qa = qpk[PA[ai]], qb = qpk[PB[ai]];
        const u32 d = pks(qa, qb);
        cs = pka(cs, pkm(d, d));
        const u32 ad = pkmaxi(d, pks(0u, d));
        const u32 h1 = pka(ad, ONEpk);
        hsum += __builtin_amdgcn_rcpf(cb0(h1)) + __builtin_amdgcn_rcpf(cb2(h1));
        key[ai] = pka(pkm(qa, EIGHTpk), qb);
    }

    // Batcher odd-even mergesort for n=32, pruned to the low 20 slots
    #pragma unroll
    for (int p = 1; p < 32; p <<= 1) {
        #pragma unroll
        for (int k = p; k >= 1; k >>= 1) {
            const int jm = k % p;
            #pragma unroll
            for (int lo = 0; lo < 20; ++lo) {
                const int hi = lo + k;
                if (hi < 20 && lo >= jm && ((lo - jm) % (2 * k)) < k &&
                    (lo / (2 * p)) == (hi / (2 * p))) {
                    ce(key[lo], key[hi]);
                }
            }
        }
    }

    u32 eq[20];
    #pragma unroll
    for (int ai = 1; ai < 20; ++ai)
        eq[ai] = pks(ONEpk, pkmin(pks(key[ai], key[ai - 1]), ONEpk));

    u32 pc = 0, ps = 0, pv[20];
    pv[0] = 0;
    #pragma unroll
    for (int ai = 1; ai < 20; ++ai) {
        pc = pkm(pka(pc, ONEpk), eq[ai]);
        pv[ai] = pc;
        ps = pka(ps, pc);
    }
    float pr0, pr1;
    {
        const u32 m = pka(pv[19], ONEpk);
        pr0 = cb0(m); pr1 = cb2(m);
    }
    u32 rc = 0;
    #pragma unroll
    for (int ai = 18; ai >= 0; --ai) {
        rc = pkm(pka(rc, ONEpk), eq[ai + 1]);
        const u32 m = pka(pka(pv[ai], rc), ONEpk);
        pr0 *= cb0(m); pr1 *= cb2(m);
    }

    const int csum = (int)(cs & 0xFFFFu) + (int)(cs >> 16);
    const int psum = (int)(ps & 0xFFFFu) + (int)(ps >> 16);
    const float lsum = __logf(pr0) + __logf(pr1);

    float fc = (float)csum * (1.f / 20.f);
    float fe = ((float)psum * 2.f + 40.f) * (1.f / 400.f);
    float fn = -(lsum + 40.f * -2.9957322736f) * (1.f / 20.f);
    float fh = hsum * (1.f / 20.f);

    // reduce over 4 ch-pairs within the wave (lane bits 4,5), then 8 waves
    fc += __shfl_xor(fc, 16); fe += __shfl_xor(fe, 16);
    fn += __shfl_xor(fn, 16); fh += __shfl_xor(fh, 16);
    fc += __shfl_xor(fc, 32); fe += __shfl_xor(fe, 32);
    fn += __shfl_xor(fn, 32); fh += __shfl_xor(fh, 32);
    const int wv = t >> 6;               // 0..7
    if ((t & 63) < 16) {
        red[wv][pxl][0] = fc; red[wv][pxl][1] = fe;
        red[wv][pxl][2] = fn; red[wv][pxl][3] = fh;
    }
    __syncthreads();
    if (t < 64) {
        const int p2 = t >> 2, f = t & 3;
        float s = 0.f;
        #pragma unroll
        for (int wq = 0; wq < 8; ++wq) s += red[wq][p2][f];
        xs[64 + f][p2] = s * (1.f / 64.f);   // g stays in LDS
    }
    __syncthreads();   // xs (centers + g) and staged weights complete

    // ---- phase 2: cv1 + cv2, thread = (px, oc) = (t&15, t>>4) ----
    {
        const int px = t & 15;
        const int oc = t >> 4;               // 0..31
        float acc1 = 0.f, acc2 = 0.f;
        #pragma unroll 4
        for (int ic = 0; ic < 68; ++ic) {
            const float v = xs[ic][px];
            acc1 += v * ws1T[ic * 33 + oc];
            acc2 += v * ws2T[ic * 33 + oc];
        }
        const int pix2 = blockIdx.x * PXB + px;
        const int bb = pix2 / HW;
        const int hw2 = pix2 - bb * HW;
        const float v1 = silu(acc1 * s1[oc] + b1[oc]);
        a[((size_t)(bb * 32 + oc)) * HW + hw2] = v1;
        aT[oc][px] = v1;
        bbuf[((size_t)(bb * 32 + oc)) * HW + hw2] = silu(acc2 * s2[oc] + b2[oc]);
    }
    __syncthreads();

    // ---- phase 3: m1, thread = (px, oc16), first 256 threads ----
    if (t < 256) {
        const int px = t & 15;
        const int oc = t >> 4;               // 0..15
        float acc = 0.f;
        #pragma unroll 4
        for (int ic = 0; ic < 32; ++ic)
            acc += aT[ic][px] * wsm1T[ic * 17 + oc];
        const int pix2 = blockIdx.x * PXB + px;
        const int bb = pix2 / HW;
        const int hw2 = pix2 - bb * HW;
        y16[((size_t)(bb * 16 + oc)) * HW + hw2] = silu(acc * sm1[oc] + bm1[oc]);
    }
}

// ---------------------------------------------------------------------------
// Kernel 2: m2 (3x3, 16->32, pad 1) + BN + SiLU + residual, then cv3
// (1x1, 64->64). Unchanged from round 6/7. block 512 = 8 waves x 64 px.
// ---------------------------------------------------------------------------
__global__ __launch_bounds__(512) void m2cv3_kernel(
    const float* __restrict__ y16, const float* __restrict__ a,
    const float* __restrict__ bbuf,
    const float* __restrict__ wm2, const float* __restrict__ sm2, const float* __restrict__ bm2,
    const float* __restrict__ wc, const float* __restrict__ sc, const float* __restrict__ bc,
    float* __restrict__ out) {
    __shared__ float ys[16][4][82];
    __shared__ float a2[32][64];
    __shared__ float bs[32][64];
    const int t = threadIdx.x;
    const int p0 = blockIdx.x * 64;
    const int bi = p0 / HW;
    const int hw0 = p0 - bi * HW;
    const int h0 = hw0 / W;

    const float* yb = y16 + (size_t)(bi * 16) * HW;
    for (int e = t; e < 16 * 4 * 82; e += 512) {
        const int ch = e / 328;
        const int rem = e - ch * 328;
        const int row = rem / 82;
        const int col = rem - row * 82;
        const int r = h0 - 1 + row;
        const int c = col - 1;
        float v = 0.f;
        if ((unsigned)r < (unsigned)H && (unsigned)c < (unsigned)W)
            v = yb[(size_t)ch * HW + r * W + c];
        ys[ch][row][col] = v;
    }
    for (int e = t; e < 32 * 64; e += 512) {
        const int ic = e >> 6, px = e & 63;
        bs[ic][px] = bbuf[((size_t)(bi * 32 + ic)) * HW + hw0 + px];
    }
    __syncthreads();

    const int lane = t & 63;
    const int wv = __builtin_amdgcn_readfirstlane(t >> 6);
    const int hw = hw0 + lane;
    const int h = hw / W;
    const int w = hw - h * W;
    const int lr = h - h0;
    const int oc0 = wv * 4;

    float acc[4] = {0.f, 0.f, 0.f, 0.f};
    #pragma unroll 2
    for (int ic = 0; ic < 16; ++ic) {
        #pragma unroll
        for (int ky = 0; ky < 3; ++ky) {
            #pragma unroll
            for (int kx = 0; kx < 3; ++kx) {
                const float v = ys[ic][lr + ky][w + kx];
                const int tap = ic * 9 + ky * 3 + kx;
                #pragma unroll
                for (int j = 0; j < 4; ++j)
                    acc[j] += v * wm2[(oc0 + j) * 144 + tap];
            }
        }
    }
    #pragma unroll
    for (int j = 0; j < 4; ++j) {
        const int oc = oc0 + j;
        a2[oc][lane] = a[((size_t)(bi * 32 + oc)) * HW + hw]
                     + silu(acc[j] * sm2[oc] + bm2[oc]);
    }
    __syncthreads();
    const int oc3 = wv * 8;
    float c_[8] = {0.f, 0.f, 0.f, 0.f, 0.f, 0.f, 0.f, 0.f};
    #pragma unroll 4
    for (int ic = 0; ic < 32; ++ic) {
        const float av = a2[ic][lane];
        const float bv = bs[ic][lane];
        #pragma unroll
        for (int j = 0; j < 8; ++j) {
            c_[j] += av * wc[(oc3 + j) * 64 + ic];
            c_[j] += bv * wc[(oc3 + j) * 64 + 32 + ic];
        }
    }
    #pragma unroll
    for (int j = 0; j < 8; ++j) {
        const int oc = oc3 + j;
        out[((size_t)(bi * 64 + oc)) * HW + hw] = silu(c_[j] * sc[oc] + bc[oc]);
    }
}

// ---------------------------------------------------------------------------
extern "C" void kernel_launch(void* const* d_in, const int* in_sizes, int n_in,
                              void* d_out, int out_size, void* d_ws, size_t ws_size,
                              hipStream_t stream) {
    const float* x    = (const float*)d_in[0];
    const float* cv1w = (const float*)d_in[1];
    const float* cv1s = (const float*)d_in[2];
    const float* cv1b = (const float*)d_in[3];
    const float* cv2w = (const float*)d_in[4];
    const float* cv2s = (const float*)d_in[5];
    const float* cv2b = (const float*)d_in[6];
    const float* m1w  = (const float*)d_in[7];
    const float* m1s  = (const float*)d_in[8];
    const float* m1b  = (const float*)d_in[9];
    const float* m2w  = (const float*)d_in[10];
    const float* m2s  = (const float*)d_in[11];
    const float* m2b  = (const float*)d_in[12];
    const float* cv3w = (const float*)d_in[13];
    const float* cv3s = (const float*)d_in[14];
    const float* cv3b = (const float*)d_in[15];

    float* ws   = (float*)d_ws;
    float* a    = ws;                 // 4*32*6400 = 819200
    float* bbuf = ws + 819200;        // 819200
    float* y16  = ws + 1638400;       // 409600 (end 2048000)

    glcm_stage1_kernel<<<NPIX / PXB, 512, 0, stream>>>(
        x, cv1w, cv1s, cv1b, cv2w, cv2s, cv2b, m1w, m1s, m1b, a, bbuf, y16);
    m2cv3_kernel<<<NPIX / 64, 512, 0, stream>>>(y16, a, bbuf, m2w, m2s, m2b,
                                                cv3w, cv3s, cv3b, (float*)d_out);
}